// Round 1
// baseline (24.837 us; speedup 1.0000x reference)
//
#include <hip/hip_runtime.h>

#define NRES   23
#define NA37   37
#define NSC    34
#define DIM    128
#define RAD2   64.0f
#define NEGINF -1000000000.0f

// Kernel 1: per-residue meta (argmax restype -> vm row, CA pos + |CA|^2) and
// S[b,j,:] = sum_a sc_emb[b,j,a,:]  (the per-residue atom-sum).
// grid = B*L blocks, 128 threads (one per d).
__global__ void k_meta_S(const float* __restrict__ aa,   // (BL,23)
                         const float* __restrict__ re,   // (BL,128)
                         const float* __restrict__ bb,   // (BL,4,3)
                         const float* __restrict__ mask, // (BL,)
                         const float* __restrict__ tbl,  // (23,37)
                         const float* __restrict__ ae,   // (37,128)
                         float* __restrict__ S,          // (BL,128)
                         float* __restrict__ meta,       // (BL,4) x,y,z,sq
                         float* __restrict__ vmb)        // (BL,34)
{
    int bi = blockIdx.x;
    int d  = threadIdx.x;

    // argmax over aa_pred with [20:] forced to NEG_INF; first-max tie-break.
    const float* aarow = aa + bi * NRES;
    int   rt   = 0;
    float best = aarow[0];
#pragma unroll
    for (int t = 1; t < NRES; ++t) {
        float v = (t < 20) ? aarow[t] : NEGINF;
        if (v > best) { best = v; rt = t; }
    }

    float m = mask[bi];
    const float* trow = tbl + rt * NA37 + 3;  // side-chain columns 3..36

    float red = re[bi * DIM + d];
    float s = 0.f;
#pragma unroll
    for (int a = 0; a < NSC; ++a) {
        float vm = trow[a] * m;
        // sc_emb[b,i,a,d] = vm * (re[d] + vm * atom_embed[a+3,d])
        s += vm * (red + vm * ae[(a + 3) * DIM + d]);
    }
    S[bi * DIM + d] = s;

    if (d < NSC) vmb[bi * NSC + d] = trow[d] * m;
    if (d == 0) {
        float x = bb[(bi * 4 + 1) * 3 + 0] * m;
        float y = bb[(bi * 4 + 1) * 3 + 1] * m;
        float z = bb[(bi * 4 + 1) * 3 + 2] * m;
        meta[bi * 4 + 0] = x;
        meta[bi * 4 + 1] = y;
        meta[bi * 4 + 2] = z;
        meta[bi * 4 + 3] = x * x + y * y + z * z;
    }
}

// Kernel 2: per-residue block. R[d] = sum_j [d2(i,j)<64] * S[b,j,d], then
// out[(i,a),d] = vm[a]>0 ? R[d] - sc_emb[i,a,d] : 0.
// grid = B*L blocks, 128 threads; dynamic LDS = 4*L floats.
__global__ void k_msg(const float* __restrict__ re,
                      const float* __restrict__ ae,
                      const float* __restrict__ S,
                      const float* __restrict__ meta,
                      const float* __restrict__ vmb,
                      float* __restrict__ out,
                      int L)
{
    int bi = blockIdx.x;
    int b  = bi / L;
    int i  = bi % L;
    int d  = threadIdx.x;

    extern __shared__ float lds[];
    float* cx = lds;
    float* cy = lds + L;
    float* cz = lds + 2 * L;
    float* cs = lds + 3 * L;
    for (int j = d; j < L; j += blockDim.x) {
        int gj = b * L + j;
        cx[j] = meta[gj * 4 + 0];
        cy[j] = meta[gj * 4 + 1];
        cz[j] = meta[gj * 4 + 2];
        cs[j] = meta[gj * 4 + 3];
    }
    __syncthreads();

    float xi = cx[i], yi = cy[i], zi = cz[i], si = cs[i];

    float r = 0.f;
    const float* Sb = S + (size_t)b * L * DIM + d;
    for (int j = 0; j < L; ++j) {
        // same algebra as the reference: sq_i + sq_j - 2*dot
        float d2 = si + cs[j] - 2.f * (xi * cx[j] + yi * cy[j] + zi * cz[j]);
        if (d2 < RAD2) r += Sb[(size_t)j * DIM];  // block-uniform branch
    }

    float red = re[bi * DIM + d];
    float* orow = out + (size_t)bi * NSC * DIM + d;
#pragma unroll
    for (int a = 0; a < NSC; ++a) {
        float vm = vmb[bi * NSC + a];
        float sc = vm * (red + vm * ae[(a + 3) * DIM + d]);
        orow[(size_t)a * DIM] = (vm > 0.f) ? (r - sc) : 0.f;
    }
}

extern "C" void kernel_launch(void* const* d_in, const int* in_sizes, int n_in,
                              void* d_out, int out_size, void* d_ws, size_t ws_size,
                              hipStream_t stream) {
    const float* aa   = (const float*)d_in[0];  // aa_pred (B,L,23)
    const float* re   = (const float*)d_in[1];  // residue_embeddings (B,L,128)
    const float* bb   = (const float*)d_in[2];  // bb_pred (B,L,4,3)
    const float* mask = (const float*)d_in[3];  // mask (B,L)
    const float* tbl  = (const float*)d_in[4];  // valid_atom37_mask (23,37)
    const float* ae   = (const float*)d_in[5];  // atom_embed (37,128)
    float* out = (float*)d_out;

    const int BL = in_sizes[3];  // B*L
    const int L  = 128;          // per reference setup (B=2, L=128)

    float* S    = (float*)d_ws;          // BL*128
    float* meta = S + (size_t)BL * DIM;  // BL*4
    float* vmb  = meta + (size_t)BL * 4; // BL*34

    k_meta_S<<<BL, DIM, 0, stream>>>(aa, re, bb, mask, tbl, ae, S, meta, vmb);
    k_msg<<<BL, DIM, 4 * L * sizeof(float), stream>>>(re, ae, S, meta, vmb, out, L);
}